// Round 3
// baseline (225.950 us; speedup 1.0000x reference)
//
#include <hip/hip_runtime.h>
#include <cstdint>
#include <cmath>

// MultiHead attention fused pipeline for MI355X (gfx950).
// B=4, T=2048, E=1024, H=16, hs=64. fp32 in/out, bf16 MFMA compute.
// Round 3: attn -> 512 blocks (2/CU, LPT-balanced qt order) + defer-max + setprio;
// qkv_gemm -> counted-vmcnt 4-buffer pipeline (raw s_barrier, never-drain vmcnt)
// with T2 XOR-swizzled LDS; cvt_w vectorized.

typedef __attribute__((ext_vector_type(8))) __bf16 bf16x8;
typedef __attribute__((ext_vector_type(4))) __bf16 bf16x4;
typedef __attribute__((ext_vector_type(4))) float f32x4;
typedef __attribute__((ext_vector_type(16))) float f32x16;

#define B_ 4
#define T_ 2048
#define E_ 1024
#define H_ 16
#define HS_ 64

__device__ __forceinline__ f32x4 mfma16(bf16x8 a, bf16x8 b, f32x4 c) {
  return __builtin_amdgcn_mfma_f32_16x16x32_bf16(a, b, c, 0, 0, 0);
}
__device__ __forceinline__ f32x16 mfma32(bf16x8 a, bf16x8 b, f32x16 c) {
  return __builtin_amdgcn_mfma_f32_32x32x16_bf16(a, b, c, 0, 0, 0);
}

__device__ __forceinline__ void gload_lds16(const void* g, void* l) {
  __builtin_amdgcn_global_load_lds(
      (const __attribute__((address_space(1))) unsigned int*)g,
      (__attribute__((address_space(3))) unsigned int*)l,
      16, 0, 0);
}

__device__ __forceinline__ unsigned cvt_pk_bf16(float lo, float hi) {
  unsigned r;
  asm("v_cvt_pk_bf16_f32 %0, %1, %2" : "=v"(r) : "v"(lo), "v"(hi));
  return r;
}
__device__ __forceinline__ void pl32swap(unsigned& a, unsigned& b) {
  asm("v_permlane32_swap_b32 %0, %1" : "+v"(a), "+v"(b));
}

// ---- convert x (fp32) -> Xb (bf16), coalesced, 4 elems/thread ----
__global__ __launch_bounds__(256) void cvt_x_kernel(const float* __restrict__ x,
                                                    __bf16* __restrict__ xb) {
  int i = (blockIdx.x * 256 + threadIdx.x) * 4;
  float4 v = *(const float4*)(x + i);
  bf16x4 o;
  o[0] = (__bf16)v.x; o[1] = (__bf16)v.y; o[2] = (__bf16)v.z; o[3] = (__bf16)v.w;
  *(bf16x4*)(xb + i) = o;
}

// ---- W[h][e][d] (fp32) -> Wt[qkv][n=h*64+d][e] (bf16, B^T layout) ----
__global__ __launch_bounds__(256) void cvt_w_kernel(const float* __restrict__ Wq,
                                                    const float* __restrict__ Wk,
                                                    const float* __restrict__ Wv,
                                                    __bf16* __restrict__ wt) {
  __shared__ float tile[64][65];
  const int e0 = blockIdx.x * 64;
  const int h = blockIdx.y;
  const int qkv = blockIdx.z;
  const int t = threadIdx.x;
  const float* W = (qkv == 0) ? Wq : (qkv == 1) ? Wk : Wv;
#pragma unroll
  for (int j = 0; j < 4; ++j) {
    int idx = j * 256 + t;
    int d4 = idx & 15, e = idx >> 4;
    float4 v = *(const float4*)&W[((size_t)(h * 1024 + e0 + e)) * 64 + d4 * 4];
    tile[d4 * 4 + 0][e] = v.x;
    tile[d4 * 4 + 1][e] = v.y;
    tile[d4 * 4 + 2][e] = v.z;
    tile[d4 * 4 + 3][e] = v.w;
  }
  __syncthreads();
#pragma unroll
  for (int j = 0; j < 2; ++j) {
    int idx = j * 256 + t;
    int e8 = idx & 7, d = idx >> 3;
    bf16x8 o;
#pragma unroll
    for (int i = 0; i < 8; ++i) o[i] = (__bf16)tile[d][e8 * 8 + i];
    *(bf16x8*)&wt[((size_t)qkv << 20) + (size_t)(h * 64 + d) * 1024 + e0 + e8 * 8] = o;
  }
}

// ---- QKV projection GEMM: 128x128 tile, BK=32, 4 waves, counted-vmcnt
//      4-buffer pipeline (prefetch depth 3 tiles), XOR-swizzled LDS. ----
__global__ __launch_bounds__(256) void qkv_gemm_kernel(
    const __bf16* __restrict__ Xb, const __bf16* __restrict__ Wt,
    __bf16* __restrict__ Qb, __bf16* __restrict__ Kb, __bf16* __restrict__ Vt) {
  __shared__ __bf16 As[4][128 * 32];
  __shared__ __bf16 Bs[4][128 * 32];
  const int qkv = blockIdx.z;
  const int m0 = blockIdx.x * 128;
  const int n0 = blockIdx.y * 128;
  const int t = threadIdx.x;
  const int lane = t & 63;
  const int w = t >> 6, wr = w >> 1, wc = w & 1;
  const int g = lane >> 4, c = lane & 15;

  const __bf16* wsrc = Wt + ((size_t)qkv << 20);
  f32x4 acc[4][4] = {};

  // staging: thread t covers row t>>2 (and +64); source col pre-swizzled so
  // linear LDS dest + swizzled read form the same involution (rule 21).
  const int srow = t >> 2;
  const int cs8 = (((t & 3) ^ (srow & 3)) << 3);
  const __bf16* gA0 = Xb + (size_t)(m0 + srow) * 1024 + cs8;
  const __bf16* gA1 = Xb + (size_t)(m0 + 64 + srow) * 1024 + cs8;
  const __bf16* gB0 = wsrc + (size_t)(n0 + srow) * 1024 + cs8;
  const __bf16* gB1 = wsrc + (size_t)(n0 + 64 + srow) * 1024 + cs8;

  auto stage = [&](int s) {
    const int b = s & 3;
    const int ko = s * 32;
    gload_lds16(gA0 + ko, &As[b][t * 8]);
    gload_lds16(gA1 + ko, &As[b][2048 + t * 8]);
    gload_lds16(gB0 + ko, &Bs[b][t * 8]);
    gload_lds16(gB1 + ko, &Bs[b][2048 + t * 8]);
  };

  stage(0); stage(1); stage(2);  // 12 loads in flight

  const int gx = (g ^ (c & 3)) << 3;  // read-side swizzle (row&3 == c&3 here)

#pragma unroll 1
  for (int kt = 0; kt < 32; ++kt) {
    // wait for tile kt's own loads (outstanding: up to 2 newer tiles = 8)
    if (kt <= 29) {
      asm volatile("s_waitcnt vmcnt(8)" ::: "memory");
    } else if (kt == 30) {
      asm volatile("s_waitcnt vmcnt(4)" ::: "memory");
    } else {
      asm volatile("s_waitcnt vmcnt(0)" ::: "memory");
    }
    __builtin_amdgcn_sched_barrier(0);
    __builtin_amdgcn_s_barrier();  // all waves confirmed tile kt resident;
                                   // all reads of buf[(kt+3)&3] done last iter
    if (kt + 3 < 32) stage(kt + 3);

    const __bf16* Ab = &As[kt & 3][0];
    const __bf16* Bb = &Bs[kt & 3][0];
    bf16x8 af[4], bfr[4];
#pragma unroll
    for (int mi = 0; mi < 4; ++mi)
      af[mi] = *(const bf16x8*)&Ab[(wr * 64 + mi * 16 + c) * 32 + gx];
#pragma unroll
    for (int ni = 0; ni < 4; ++ni)
      bfr[ni] = *(const bf16x8*)&Bb[(wc * 64 + ni * 16 + c) * 32 + gx];
    __builtin_amdgcn_s_setprio(1);
#pragma unroll
    for (int mi = 0; mi < 4; ++mi)
#pragma unroll
      for (int ni = 0; ni < 4; ++ni)
        acc[mi][ni] = mfma16(af[mi], bfr[ni], acc[mi][ni]);
    __builtin_amdgcn_s_setprio(0);
    __builtin_amdgcn_sched_barrier(0);
  }

  const int mbase = m0 + wr * 64 + g * 4;
  const int nbase = n0 + wc * 64 + c;
  if (qkv < 2) {
    __bf16* dst = (qkv == 0) ? Qb : Kb;  // [B][H][T][64]
#pragma unroll
    for (int mi = 0; mi < 4; ++mi) {
#pragma unroll
      for (int ni = 0; ni < 4; ++ni) {
        int n = nbase + ni * 16;
        int h = n >> 6, d = n & 63;
#pragma unroll
        for (int r = 0; r < 4; ++r) {
          int m = mbase + mi * 16 + r;
          int b = m >> 11, tt = m & 2047;
          dst[(((size_t)b * H_ + h) * T_ + tt) * HS_ + d] = (__bf16)acc[mi][ni][r];
        }
      }
    }
  } else {
    // V stored transposed: Vt[B][H][d][t]
#pragma unroll
    for (int mi = 0; mi < 4; ++mi) {
      int m = mbase + mi * 16;
      int b = m >> 11, tt = m & 2047;
#pragma unroll
      for (int ni = 0; ni < 4; ++ni) {
        int n = nbase + ni * 16;
        int h = n >> 6, d = n & 63;
        bf16x4 pk;
        pk[0] = (__bf16)acc[mi][ni][0];
        pk[1] = (__bf16)acc[mi][ni][1];
        pk[2] = (__bf16)acc[mi][ni][2];
        pk[3] = (__bf16)acc[mi][ni][3];
        *(bf16x4*)&Vt[(((size_t)b * H_ + h) * HS_ + d) * T_ + tt] = pk;
      }
    }
  }
}

// ---- fused causal attention ----
// 512 blocks x 512 threads; block = (bh, one 256-row q-tile). 8 waves x 32 rows.
// qt order {7,6,5,4,0,1,2,3}: co-resident pairs (j, j+256) sum to 9 work units.
// bh = j&63 -> all 8 blocks of a (b,h) on one XCD (K/V 512KB x 8 = 4MB = L2).
__global__ __launch_bounds__(512) void attn_kernel(
    const __bf16* __restrict__ Qb, const __bf16* __restrict__ Kb,
    const __bf16* __restrict__ Vt, float* __restrict__ out) {
  __shared__ __bf16 Ks[2][64 * 64];
  __shared__ __bf16 Vs[2][64 * 64];

  const int j = blockIdx.x;
  const int g8 = j >> 6;
  const int qt = (g8 < 4) ? (7 - g8) : (g8 - 4);
  const int bh = j & 63;
  const int b = bh >> 4, hh = bh & 15;
  const int t = threadIdx.x;
  const int lane = t & 63, w = t >> 6;
  const int lr = lane & 31, h = lane >> 5;

  const __bf16* Qg = Qb + (size_t)bh * T_ * HS_;
  const __bf16* Kg = Kb + (size_t)bh * T_ * HS_;
  const __bf16* Vg = Vt + (size_t)bh * HS_ * T_;

  const int srow = t >> 3;
  const int scb = ((t & 7) << 4) ^ ((srow & 7) << 4);   // pre-swizzled src col
  const int kxor = (lr & 7) << 4;                       // read-side swizzle

  const float C2 = 0.04508422f;  // log2(e)/32

  const int qbase = qt * 256;
  const int NT = (qt + 1) * 4;
  const int tqg = qbase + w * 32 + lr;

  const __bf16* Qrow = Qg + (size_t)tqg * 64;
  bf16x8 qf0 = *(const bf16x8*)(Qrow + h * 8);
  bf16x8 qf1 = *(const bf16x8*)(Qrow + 16 + h * 8);
  bf16x8 qf2 = *(const bf16x8*)(Qrow + 32 + h * 8);
  bf16x8 qf3 = *(const bf16x8*)(Qrow + 48 + h * 8);

  f32x16 o0 = {}, o1 = {};
  float m_run = -INFINITY, l_run = 0.f;
  int cur = 0;

  gload_lds16((const char*)Kg + (size_t)srow * 128 + scb, (char*)&Ks[0][0] + t * 16);
  gload_lds16((const char*)Vg + (size_t)srow * 4096 + scb, (char*)&Vs[0][0] + t * 16);
  __syncthreads();

#pragma unroll 1
  for (int kt = 0; kt < NT; ++kt) {
    const int kbase = kt * 64;
    if (kt + 1 < NT) {  // prefetch next tile into buf cur^1
      const int nb = cur ^ 1;
      gload_lds16((const char*)Kg + (size_t)(kbase + 64 + srow) * 128 + scb,
                  (char*)&Ks[nb][0] + t * 16);
      gload_lds16((const char*)Vg + (size_t)srow * 4096 + (size_t)(kbase + 64) * 2 + scb,
                  (char*)&Vs[nb][0] + t * 16);
    }
    if (kbase <= qbase + w * 32 + 31) {  // wave participates (causal)
      const char* KsB = (const char*)&Ks[cur][0];
      const char* VsB = (const char*)&Vs[cur][0];

      // --- QK^T (swapped): S^T[tk][tq] ---
      f32x16 s0 = {}, s1 = {};
      __builtin_amdgcn_s_setprio(1);
#pragma unroll
      for (int ds = 0; ds < 4; ++ds) {
        bf16x8 k0 = *(const bf16x8*)(KsB + ((lr * 128 + ds * 32 + h * 16) ^ kxor));
        bf16x8 k1 = *(const bf16x8*)(KsB + (((lr + 32) * 128 + ds * 32 + h * 16) ^ kxor));
        bf16x8 qd = (ds == 0) ? qf0 : (ds == 1) ? qf1 : (ds == 2) ? qf2 : qf3;
        s0 = mfma32(k0, qd, s0);
        s1 = mfma32(k1, qd, s1);
      }
      __builtin_amdgcn_s_setprio(0);

      // --- causal mask (diagonal tiles only) ---
      if (kbase + 63 > qbase + w * 32) {
#pragma unroll
        for (int r = 0; r < 16; ++r) {
          int tk0 = kbase + (r & 3) + 8 * (r >> 2) + 4 * h;
          if (tk0 > tqg) s0[r] = -INFINITY;
          if (tk0 + 32 > tqg) s1[r] = -INFINITY;
        }
      }

      // --- online softmax with defer-max (T13) ---
      float mx = s0[0];
#pragma unroll
      for (int r = 1; r < 16; ++r) mx = fmaxf(mx, s0[r]);
#pragma unroll
      for (int r = 0; r < 16; ++r) mx = fmaxf(mx, s1[r]);
      mx = fmaxf(mx, __shfl_xor(mx, 32));
      if (!__all(mx - m_run <= 256.f)) {   // 256 raw = e^8-ish bound on P
        float mn = fmaxf(m_run, mx);
        float fac = __builtin_amdgcn_exp2f((m_run - mn) * C2);
        l_run *= fac;
#pragma unroll
        for (int r = 0; r < 16; ++r) { o0[r] *= fac; o1[r] *= fac; }
        m_run = mn;
      }
      float sum = 0.f;
#pragma unroll
      for (int r = 0; r < 16; ++r) {
        s0[r] = __builtin_amdgcn_exp2f((s0[r] - m_run) * C2);
        s1[r] = __builtin_amdgcn_exp2f((s1[r] - m_run) * C2);
        sum += s0[r] + s1[r];
      }
      sum += __shfl_xor(sum, 32);
      l_run += sum;

      // --- P -> bf16 B-frags (cvt_pk + permlane32_swap), PV: D[d][tq] ---
      __builtin_amdgcn_s_setprio(1);
#pragma unroll
      for (int blk = 0; blk < 4; ++blk) {
        f32x16& sv = (blk < 2) ? s0 : s1;
        const int off = (blk & 1) * 8;
        unsigned u0 = cvt_pk_bf16(sv[off + 0], sv[off + 1]);
        unsigned u1 = cvt_pk_bf16(sv[off + 2], sv[off + 3]);
        unsigned u2 = cvt_pk_bf16(sv[off + 4], sv[off + 5]);
        unsigned u3 = cvt_pk_bf16(sv[off + 6], sv[off + 7]);
        pl32swap(u0, u2);
        pl32swap(u1, u3);
        union { unsigned u[4]; bf16x8 v; } pb;
        pb.u[0] = u0; pb.u[1] = u1; pb.u[2] = u2; pb.u[3] = u3;
        bf16x8 v0 = *(const bf16x8*)(VsB + ((lr * 128 + blk * 32 + h * 16) ^ kxor));
        bf16x8 v1 = *(const bf16x8*)(VsB + (((lr + 32) * 128 + blk * 32 + h * 16) ^ kxor));
        o0 = mfma32(v0, pb.v, o0);
        o1 = mfma32(v1, pb.v, o1);
      }
      __builtin_amdgcn_s_setprio(0);
    }
    __syncthreads();  // staging landed + all waves done with buf[cur]
    cur ^= 1;
  }

  // --- epilogue ---
  const float inv_l = 1.0f / l_run;
  float* orow = out + ((size_t)b * T_ + tqg) * E_ + hh * 64;
#pragma unroll
  for (int d0i = 0; d0i < 2; ++d0i) {
#pragma unroll
    for (int qd = 0; qd < 4; ++qd) {
      float4 v;
      const f32x16& ac = d0i ? o1 : o0;
      v.x = ac[qd * 4 + 0] * inv_l;
      v.y = ac[qd * 4 + 1] * inv_l;
      v.z = ac[qd * 4 + 2] * inv_l;
      v.w = ac[qd * 4 + 3] * inv_l;
      *(float4*)(orow + d0i * 32 + qd * 8 + 4 * h) = v;
    }
  }
}

extern "C" void kernel_launch(void* const* d_in, const int* in_sizes, int n_in,
                              void* d_out, int out_size, void* d_ws, size_t ws_size,
                              hipStream_t stream) {
  const float* x = (const float*)d_in[0];
  const float* Wq = (const float*)d_in[1];
  const float* Wk = (const float*)d_in[2];
  const float* Wv = (const float*)d_in[3];
  float* out = (float*)d_out;

  char* ws = (char*)d_ws;
  __bf16* Xb = (__bf16*)ws;                    // 16 MiB
  __bf16* Wt = (__bf16*)(ws + (16u << 20));    //  6 MiB
  __bf16* Qb = (__bf16*)(ws + (22u << 20));    // 16 MiB
  __bf16* Kb = (__bf16*)(ws + (38u << 20));    // 16 MiB
  __bf16* Vt = (__bf16*)(ws + (54u << 20));    // 16 MiB

  cvt_x_kernel<<<8192, 256, 0, stream>>>(x, Xb);
  cvt_w_kernel<<<dim3(16, 16, 3), 256, 0, stream>>>(Wq, Wk, Wv, Wt);
  qkv_gemm_kernel<<<dim3(64, 8, 3), 256, 0, stream>>>(Xb, Wt, Qb, Kb, Vt);
  attn_kernel<<<dim3(512), 512, 0, stream>>>(Qb, Kb, Vt, out);
}

// Round 5
// 211.891 us; speedup vs baseline: 1.0663x; 1.0663x over previous
//
#include <hip/hip_runtime.h>
#include <cstdint>
#include <cmath>

// MultiHead attention fused pipeline for MI355X (gfx950).
// B=4, T=2048, E=1024, H=16, hs=64. fp32 in/out, bf16 MFMA compute.
// Round 4 (resubmit; round-4 bench never ran — acquisition timeout):
// both hot kernels -> 3-slot counted-vmcnt pipelines (depth-2 prefetch,
// one raw s_barrier per tile, never vmcnt(0) mid-loop, small LDS for occupancy).

typedef __attribute__((ext_vector_type(8))) __bf16 bf16x8;
typedef __attribute__((ext_vector_type(4))) __bf16 bf16x4;
typedef __attribute__((ext_vector_type(4))) float f32x4;
typedef __attribute__((ext_vector_type(16))) float f32x16;

#define B_ 4
#define T_ 2048
#define E_ 1024
#define H_ 16
#define HS_ 64

__device__ __forceinline__ f32x4 mfma16(bf16x8 a, bf16x8 b, f32x4 c) {
  return __builtin_amdgcn_mfma_f32_16x16x32_bf16(a, b, c, 0, 0, 0);
}
__device__ __forceinline__ f32x16 mfma32(bf16x8 a, bf16x8 b, f32x16 c) {
  return __builtin_amdgcn_mfma_f32_32x32x16_bf16(a, b, c, 0, 0, 0);
}

__device__ __forceinline__ void gload_lds16(const void* g, void* l) {
  __builtin_amdgcn_global_load_lds(
      (const __attribute__((address_space(1))) unsigned int*)g,
      (__attribute__((address_space(3))) unsigned int*)l,
      16, 0, 0);
}

__device__ __forceinline__ unsigned cvt_pk_bf16(float lo, float hi) {
  unsigned r;
  asm("v_cvt_pk_bf16_f32 %0, %1, %2" : "=v"(r) : "v"(lo), "v"(hi));
  return r;
}
__device__ __forceinline__ void pl32swap(unsigned& a, unsigned& b) {
  asm("v_permlane32_swap_b32 %0, %1" : "+v"(a), "+v"(b));
}
__device__ __forceinline__ void barrier_asm() {
  asm volatile("s_barrier" ::: "memory");
}

// ---- convert x (fp32) -> Xb (bf16) ----
__global__ __launch_bounds__(256) void cvt_x_kernel(const float* __restrict__ x,
                                                    __bf16* __restrict__ xb) {
  int i = (blockIdx.x * 256 + threadIdx.x) * 4;
  float4 v = *(const float4*)(x + i);
  bf16x4 o;
  o[0] = (__bf16)v.x; o[1] = (__bf16)v.y; o[2] = (__bf16)v.z; o[3] = (__bf16)v.w;
  *(bf16x4*)(xb + i) = o;
}

// ---- W[h][e][d] (fp32) -> Wt[qkv][n=h*64+d][e] (bf16, B^T layout) ----
__global__ __launch_bounds__(256) void cvt_w_kernel(const float* __restrict__ Wq,
                                                    const float* __restrict__ Wk,
                                                    const float* __restrict__ Wv,
                                                    __bf16* __restrict__ wt) {
  __shared__ float tile[64][65];
  const int e0 = blockIdx.x * 64;
  const int h = blockIdx.y;
  const int qkv = blockIdx.z;
  const int t = threadIdx.x;
  const float* W = (qkv == 0) ? Wq : (qkv == 1) ? Wk : Wv;
#pragma unroll
  for (int j = 0; j < 4; ++j) {
    int idx = j * 256 + t;
    int d4 = idx & 15, e = idx >> 4;
    float4 v = *(const float4*)&W[((size_t)(h * 1024 + e0 + e)) * 64 + d4 * 4];
    tile[d4 * 4 + 0][e] = v.x;
    tile[d4 * 4 + 1][e] = v.y;
    tile[d4 * 4 + 2][e] = v.z;
    tile[d4 * 4 + 3][e] = v.w;
  }
  __syncthreads();
#pragma unroll
  for (int j = 0; j < 2; ++j) {
    int idx = j * 256 + t;
    int e8 = idx & 7, d = idx >> 3;
    bf16x8 o;
#pragma unroll
    for (int i = 0; i < 8; ++i) o[i] = (__bf16)tile[d][e8 * 8 + i];
    *(bf16x8*)&wt[((size_t)qkv << 20) + (size_t)(h * 64 + d) * 1024 + e0 + e8 * 8] = o;
  }
}

// ---- QKV projection GEMM: 128x128 tile, BK=32, 4 waves.
//      3-slot counted-vmcnt pipeline (depth-2), 48KB LDS -> 3 blocks/CU. ----
__global__ __launch_bounds__(256) void qkv_gemm_kernel(
    const __bf16* __restrict__ Xb, const __bf16* __restrict__ Wt,
    __bf16* __restrict__ Qb, __bf16* __restrict__ Kb, __bf16* __restrict__ Vt) {
  __shared__ __bf16 As[3][128 * 32];
  __shared__ __bf16 Bs[3][128 * 32];
  const int qkv = blockIdx.z;
  const int m0 = blockIdx.x * 128;
  const int n0 = blockIdx.y * 128;
  const int t = threadIdx.x;
  const int lane = t & 63;
  const int w = t >> 6, wr = w >> 1, wc = w & 1;
  const int g = lane >> 4, c = lane & 15;

  const __bf16* wsrc = Wt + ((size_t)qkv << 20);
  f32x4 acc[4][4] = {};

  // staging: thread t covers row t>>2 (and +64); source col pre-swizzled so
  // linear LDS dest + swizzled read form the same involution (rule 21).
  const int srow = t >> 2;
  const int cs8 = (((t & 3) ^ (srow & 3)) << 3);
  const __bf16* gA0 = Xb + (size_t)(m0 + srow) * 1024 + cs8;
  const __bf16* gA1 = Xb + (size_t)(m0 + 64 + srow) * 1024 + cs8;
  const __bf16* gB0 = wsrc + (size_t)(n0 + srow) * 1024 + cs8;
  const __bf16* gB1 = wsrc + (size_t)(n0 + 64 + srow) * 1024 + cs8;

  auto stage = [&](int s, int slot) {
    const int ko = s * 32;
    gload_lds16(gA0 + ko, &As[slot][t * 8]);
    gload_lds16(gA1 + ko, &As[slot][2048 + t * 8]);
    gload_lds16(gB0 + ko, &Bs[slot][t * 8]);
    gload_lds16(gB1 + ko, &Bs[slot][2048 + t * 8]);
  };

  stage(0, 0);
  stage(1, 1);  // 8 loads in flight

  const int gx = (g ^ (c & 3)) << 3;  // read-side swizzle (row&3 == c&3)
  int slot = 0;

#pragma unroll 1
  for (int kt = 0; kt < 32; ++kt) {
    // retire tile kt's own 4 loads; keep tile kt+1's in flight
    if (kt < 31) {
      asm volatile("s_waitcnt vmcnt(4)" ::: "memory");
    } else {
      asm volatile("s_waitcnt vmcnt(0)" ::: "memory");
    }
    __builtin_amdgcn_sched_barrier(0);
    barrier_asm();  // tile kt resident in all waves' view; iter kt-1 reads done
    if (kt + 2 < 32) {
      int ns = slot + 2; if (ns >= 3) ns -= 3;
      stage(kt + 2, ns);  // ns's previous occupant (tile kt-1) already read
    }

    const __bf16* Ab = &As[slot][0];
    const __bf16* Bb = &Bs[slot][0];
    bf16x8 af[4], bfr[4];
#pragma unroll
    for (int mi = 0; mi < 4; ++mi)
      af[mi] = *(const bf16x8*)&Ab[(wr * 64 + mi * 16 + c) * 32 + gx];
#pragma unroll
    for (int ni = 0; ni < 4; ++ni)
      bfr[ni] = *(const bf16x8*)&Bb[(wc * 64 + ni * 16 + c) * 32 + gx];
    __builtin_amdgcn_s_setprio(1);
#pragma unroll
    for (int mi = 0; mi < 4; ++mi)
#pragma unroll
      for (int ni = 0; ni < 4; ++ni)
        acc[mi][ni] = mfma16(af[mi], bfr[ni], acc[mi][ni]);
    __builtin_amdgcn_s_setprio(0);
    __builtin_amdgcn_sched_barrier(0);
    slot = (slot == 2) ? 0 : slot + 1;
  }

  const int mbase = m0 + wr * 64 + g * 4;
  const int nbase = n0 + wc * 64 + c;
  if (qkv < 2) {
    __bf16* dst = (qkv == 0) ? Qb : Kb;  // [B][H][T][64]
#pragma unroll
    for (int mi = 0; mi < 4; ++mi) {
#pragma unroll
      for (int ni = 0; ni < 4; ++ni) {
        int n = nbase + ni * 16;
        int h = n >> 6, d = n & 63;
#pragma unroll
        for (int r = 0; r < 4; ++r) {
          int m = mbase + mi * 16 + r;
          int b = m >> 11, tt = m & 2047;
          dst[(((size_t)b * H_ + h) * T_ + tt) * HS_ + d] = (__bf16)acc[mi][ni][r];
        }
      }
    }
  } else {
    // V stored transposed: Vt[B][H][d][t]
#pragma unroll
    for (int mi = 0; mi < 4; ++mi) {
      int m = mbase + mi * 16;
      int b = m >> 11, tt = m & 2047;
#pragma unroll
      for (int ni = 0; ni < 4; ++ni) {
        int n = nbase + ni * 16;
        int h = n >> 6, d = n & 63;
        bf16x4 pk;
        pk[0] = (__bf16)acc[mi][ni][0];
        pk[1] = (__bf16)acc[mi][ni][1];
        pk[2] = (__bf16)acc[mi][ni][2];
        pk[3] = (__bf16)acc[mi][ni][3];
        *(bf16x4*)&Vt[(((size_t)b * H_ + h) * HS_ + d) * T_ + tt] = pk;
      }
    }
  }
}

// ---- fused causal attention ----
// 512 blocks x 512 threads; block = (bh, one 256-row q-tile). 8 waves x 32 rows.
// qt order {7,6,5,4,0,1,2,3}: co-resident pairs (j, j+256) sum to 9 work units.
// bh = j&63 -> all 8 blocks of a (b,h) on one XCD.
// 3-slot counted-vmcnt K/V pipeline: 1 barrier/tile, no mid-loop vmcnt(0).
__global__ __launch_bounds__(512) void attn_kernel(
    const __bf16* __restrict__ Qb, const __bf16* __restrict__ Kb,
    const __bf16* __restrict__ Vt, float* __restrict__ out) {
  __shared__ __bf16 Ks[3][64 * 64];
  __shared__ __bf16 Vs[3][64 * 64];

  const int j = blockIdx.x;
  const int g8 = j >> 6;
  const int qt = (g8 < 4) ? (7 - g8) : (g8 - 4);
  const int bh = j & 63;
  const int b = bh >> 4, hh = bh & 15;
  const int t = threadIdx.x;
  const int lane = t & 63, w = t >> 6;
  const int lr = lane & 31, h = lane >> 5;

  const __bf16* Qg = Qb + (size_t)bh * T_ * HS_;
  const __bf16* Kg = Kb + (size_t)bh * T_ * HS_;
  const __bf16* Vg = Vt + (size_t)bh * HS_ * T_;

  const int srow = t >> 3;
  const int scb = ((t & 7) << 4) ^ ((srow & 7) << 4);   // pre-swizzled src col
  const int kxor = (lr & 7) << 4;                       // read-side swizzle

  // stage tile s (64 kv cols) into slot: K rows tk, V^T rows d
  auto stageKV = [&](int s, int slot) {
    gload_lds16((const char*)Kg + (size_t)(s * 64 + srow) * 128 + scb,
                (char*)&Ks[slot][0] + t * 16);
    gload_lds16((const char*)Vg + (size_t)srow * 4096 + s * 128 + scb,
                (char*)&Vs[slot][0] + t * 16);
  };

  const float C2 = 0.04508422f;  // log2(e)/32

  const int qbase = qt * 256;
  const int NT = (qt + 1) * 4;
  const int tqg = qbase + w * 32 + lr;

  const __bf16* Qrow = Qg + (size_t)tqg * 64;
  bf16x8 qf0 = *(const bf16x8*)(Qrow + h * 8);
  bf16x8 qf1 = *(const bf16x8*)(Qrow + 16 + h * 8);
  bf16x8 qf2 = *(const bf16x8*)(Qrow + 32 + h * 8);
  bf16x8 qf3 = *(const bf16x8*)(Qrow + 48 + h * 8);

  f32x16 o0 = {}, o1 = {};
  float m_run = -INFINITY, l_run = 0.f;

  stageKV(0, 0);
  stageKV(1, 1);  // 4 loads in flight (+ Q loads, retired by first wait)
  int slot = 0;

#pragma unroll 1
  for (int kt = 0; kt < NT; ++kt) {
    const int kbase = kt * 64;
    // retire tile kt's own 2 loads; keep tile kt+1's 2 in flight
    if (kt + 1 < NT) {
      asm volatile("s_waitcnt vmcnt(2)" ::: "memory");
    } else {
      asm volatile("s_waitcnt vmcnt(0)" ::: "memory");
    }
    __builtin_amdgcn_sched_barrier(0);
    barrier_asm();  // tile kt resident; iter kt-1 reads done in all waves
    if (kt + 2 < NT) {
      int ns = slot + 2; if (ns >= 3) ns -= 3;
      stageKV(kt + 2, ns);
    }

    if (kbase <= qbase + w * 32 + 31) {  // wave participates (causal)
      const char* KsB = (const char*)&Ks[slot][0];
      const char* VsB = (const char*)&Vs[slot][0];

      // --- QK^T (swapped): S^T[tk][tq] ---
      f32x16 s0 = {}, s1 = {};
      __builtin_amdgcn_s_setprio(1);
#pragma unroll
      for (int ds = 0; ds < 4; ++ds) {
        bf16x8 k0 = *(const bf16x8*)(KsB + ((lr * 128 + ds * 32 + h * 16) ^ kxor));
        bf16x8 k1 = *(const bf16x8*)(KsB + (((lr + 32) * 128 + ds * 32 + h * 16) ^ kxor));
        bf16x8 qd = (ds == 0) ? qf0 : (ds == 1) ? qf1 : (ds == 2) ? qf2 : qf3;
        s0 = mfma32(k0, qd, s0);
        s1 = mfma32(k1, qd, s1);
      }
      __builtin_amdgcn_s_setprio(0);

      // --- causal mask (diagonal tiles only) ---
      if (kbase + 63 > qbase + w * 32) {
#pragma unroll
        for (int r = 0; r < 16; ++r) {
          int tk0 = kbase + (r & 3) + 8 * (r >> 2) + 4 * h;
          if (tk0 > tqg) s0[r] = -INFINITY;
          if (tk0 + 32 > tqg) s1[r] = -INFINITY;
        }
      }

      // --- online softmax with defer-max (T13) ---
      float mx = s0[0];
#pragma unroll
      for (int r = 1; r < 16; ++r) mx = fmaxf(mx, s0[r]);
#pragma unroll
      for (int r = 0; r < 16; ++r) mx = fmaxf(mx, s1[r]);
      mx = fmaxf(mx, __shfl_xor(mx, 32));
      if (!__all(mx - m_run <= 256.f)) {
        float mn = fmaxf(m_run, mx);
        float fac = __builtin_amdgcn_exp2f((m_run - mn) * C2);
        l_run *= fac;
#pragma unroll
        for (int r = 0; r < 16; ++r) { o0[r] *= fac; o1[r] *= fac; }
        m_run = mn;
      }
      float sum = 0.f;
#pragma unroll
      for (int r = 0; r < 16; ++r) {
        s0[r] = __builtin_amdgcn_exp2f((s0[r] - m_run) * C2);
        s1[r] = __builtin_amdgcn_exp2f((s1[r] - m_run) * C2);
        sum += s0[r] + s1[r];
      }
      sum += __shfl_xor(sum, 32);
      l_run += sum;

      // --- P -> bf16 B-frags (cvt_pk + permlane32_swap), PV: D[d][tq] ---
      __builtin_amdgcn_s_setprio(1);
#pragma unroll
      for (int blk = 0; blk < 4; ++blk) {
        f32x16& sv = (blk < 2) ? s0 : s1;
        const int off = (blk & 1) * 8;
        unsigned u0 = cvt_pk_bf16(sv[off + 0], sv[off + 1]);
        unsigned u1 = cvt_pk_bf16(sv[off + 2], sv[off + 3]);
        unsigned u2 = cvt_pk_bf16(sv[off + 4], sv[off + 5]);
        unsigned u3 = cvt_pk_bf16(sv[off + 6], sv[off + 7]);
        pl32swap(u0, u2);
        pl32swap(u1, u3);
        union { unsigned u[4]; bf16x8 v; } pb;
        pb.u[0] = u0; pb.u[1] = u1; pb.u[2] = u2; pb.u[3] = u3;
        bf16x8 v0 = *(const bf16x8*)(VsB + ((lr * 128 + blk * 32 + h * 16) ^ kxor));
        bf16x8 v1 = *(const bf16x8*)(VsB + (((lr + 32) * 128 + blk * 32 + h * 16) ^ kxor));
        o0 = mfma32(v0, pb.v, o0);
        o1 = mfma32(v1, pb.v, o1);
      }
      __builtin_amdgcn_s_setprio(0);
    }
    slot = (slot == 2) ? 0 : slot + 1;
  }

  // --- epilogue ---
  const float inv_l = 1.0f / l_run;
  float* orow = out + ((size_t)b * T_ + tqg) * E_ + hh * 64;
#pragma unroll
  for (int d0i = 0; d0i < 2; ++d0i) {
#pragma unroll
    for (int qd = 0; qd < 4; ++qd) {
      float4 v;
      const f32x16& ac = d0i ? o1 : o0;
      v.x = ac[qd * 4 + 0] * inv_l;
      v.y = ac[qd * 4 + 1] * inv_l;
      v.z = ac[qd * 4 + 2] * inv_l;
      v.w = ac[qd * 4 + 3] * inv_l;
      *(float4*)(orow + d0i * 32 + qd * 8 + 4 * h) = v;
    }
  }
}

extern "C" void kernel_launch(void* const* d_in, const int* in_sizes, int n_in,
                              void* d_out, int out_size, void* d_ws, size_t ws_size,
                              hipStream_t stream) {
  const float* x = (const float*)d_in[0];
  const float* Wq = (const float*)d_in[1];
  const float* Wk = (const float*)d_in[2];
  const float* Wv = (const float*)d_in[3];
  float* out = (float*)d_out;

  char* ws = (char*)d_ws;
  __bf16* Xb = (__bf16*)ws;                    // 16 MiB
  __bf16* Wt = (__bf16*)(ws + (16u << 20));    //  6 MiB
  __bf16* Qb = (__bf16*)(ws + (22u << 20));    // 16 MiB
  __bf16* Kb = (__bf16*)(ws + (38u << 20));    // 16 MiB
  __bf16* Vt = (__bf16*)(ws + (54u << 20));    // 16 MiB

  cvt_x_kernel<<<8192, 256, 0, stream>>>(x, Xb);
  cvt_w_kernel<<<dim3(16, 16, 3), 256, 0, stream>>>(Wq, Wk, Wv, Wt);
  qkv_gemm_kernel<<<dim3(64, 8, 3), 256, 0, stream>>>(Xb, Wt, Qb, Kb, Vt);
  attn_kernel<<<dim3(512), 512, 0, stream>>>(Qb, Kb, Vt, out);
}